// Round 7
// baseline (578.933 us; speedup 1.0000x reference)
//
#include <hip/hip_runtime.h>

typedef __bf16 bf16_t;
typedef __attribute__((ext_vector_type(8))) __bf16 bf16x8;
typedef __attribute__((ext_vector_type(4))) float floatx4;

#define T_SEQ 2048
#define HID 3584
#define NH 28
#define NKV 4
#define HD 128
#define GQA 7
#define SCALE_F 0.08838834764831845f
// SCALE_F * log2(e): QK^T directly in log2 domain (exp2 = 1 instr)
#define QSCALE_LOG2 0.1275179100693744f

// ---------------- fp32 -> bf16 conversion (n % 2048 == 0) ----------------
__global__ void conv_bf_k(const float* __restrict__ src, bf16_t* __restrict__ dst, long n) {
  const long i = ((long)blockIdx.x * 256 + threadIdx.x) * 8;
  if (i >= n) return;
  const floatx4 a = *(const floatx4*)(src + i);
  const floatx4 b = *(const floatx4*)(src + i + 4);
  bf16x8 r;
  r[0] = (bf16_t)a[0]; r[1] = (bf16_t)a[1]; r[2] = (bf16_t)a[2]; r[3] = (bf16_t)a[3];
  r[4] = (bf16_t)b[0]; r[5] = (bf16_t)b[1]; r[6] = (bf16_t)b[2]; r[7] = (bf16_t)b[3];
  *(bf16x8*)(dst + i) = r;
}

// ---------------- transposing fp32 -> bf16: dst[N][K] = (bf16)src[K][N]^T ----------------
__global__ __launch_bounds__(256) void tconv_k(const float* __restrict__ src,
                                               bf16_t* __restrict__ dst, long N, long K) {
  __shared__ alignas(16) bf16_t t[64][72];
  const long k0 = (long)blockIdx.y * 64, n0 = (long)blockIdx.x * 64;
  const int tid = threadIdx.x;
  const int rr = tid >> 4;
  const int cc = (tid & 15) * 4;
#pragma unroll
  for (int i = 0; i < 4; ++i) {
    const int r = rr + i * 16;
    const floatx4 v = *(const floatx4*)(src + (k0 + r) * N + n0 + cc);
#pragma unroll
    for (int j = 0; j < 4; ++j) t[cc + j][r] = (bf16_t)v[j];
  }
  __syncthreads();
#pragma unroll
  for (int i = 0; i < 2; ++i) {
    const int J = i * 256 + tid;
    const int n = J >> 3, c8 = (J & 7) * 8;
    *(bf16x8*)(dst + (n0 + n) * K + k0 + c8) = *(const bf16x8*)(&t[n][c8]);
  }
}

// load 8 contiguous elements as bf16x8, converting from fp32 if f32 is set
__device__ __forceinline__ bf16x8 ld8(const void* p, long idx, bool f32) {
  if (f32) {
    const float* q = (const float*)p + idx;
    const floatx4 u = *(const floatx4*)q;
    const floatx4 v = *(const floatx4*)(q + 4);
    bf16x8 r;
    r[0] = (bf16_t)u[0]; r[1] = (bf16_t)u[1]; r[2] = (bf16_t)u[2]; r[3] = (bf16_t)u[3];
    r[4] = (bf16_t)v[0]; r[5] = (bf16_t)v[1]; r[6] = (bf16_t)v[2]; r[7] = (bf16_t)v[3];
    return r;
  }
  return *(const bf16x8*)((const bf16_t*)p + idx);
}

__device__ __forceinline__ void gld16(const bf16_t* g, bf16_t* l) {
  __builtin_amdgcn_global_load_lds(
      (const __attribute__((address_space(1))) unsigned int*)(const void*)g,
      (__attribute__((address_space(3))) unsigned int*)(void*)l, 16, 0, 0);
}

// ---------------- GEMM v2 (fast path): 256x256 tile, BK=64, 8 waves, deep pipeline ----
// C[M][N] = A[M][K] @ Bt[N][K]^T (+fp32 bias). Template per guide §5 (256² 8-phase
// class): 512 threads = 8 waves (2M x 4N), per-wave output 128x64 (acc[8][4]),
// LDS 128KB = 2 dbuf x (A[256][64] + B[256][64]) bf16. Staging: 8 global_load_lds
// (16B)/thread/K-tile, counted vmcnt(8) + raw s_barrier (cur tile's loads done,
// next tile's 8 stay in flight across the barrier — attn5/R6-proven discipline).
// Chunk swizzle (rule #21): LDS slot (row, s) holds global chunk s ^ (row&7);
// applied on the per-lane GLOBAL source (dest lane-linear) and on ds_read side.
// Reads: 64 lanes = 16 rows x 4 quads, slot = (ks*4+quad) ^ (col&7) -> all 8
// 16B-slots covered exactly twice -> 2-way (free). Loads stay 128B-coalesced
// (slot-permutation within a row). Per K-tile: 2 sub-phases {12 ds_read_b128 ->
// setprio(1) -> 32 MFMA -> setprio(0)}.
// mode 0: bf16 C. mode 1: fp32 C. mode 3: fused QKV epilogue (cc<3584 -> Cv bf16
// [row][ldc]; 3584<=cc<4096 -> Cv2[row][512]; cc>=4096 -> Cv2+1048576 transposed
// [cc-4096][T_SEQ]).
__global__ __launch_bounds__(512, 2) void gemm8_k(
    const bf16_t* __restrict__ A, long lda,
    const bf16_t* __restrict__ Bt, long ldb,
    const float* __restrict__ bias, void* Cv, long ldc,
    int K, int mode, void* Cv2) {
  __shared__ alignas(16) bf16_t ldsA[2][256 * 64];  // 32KB x2
  __shared__ alignas(16) bf16_t ldsB[2][256 * 64];  // 32KB x2
  const int tid = threadIdx.x;
  const int lane = tid & 63;
  const int w = tid >> 6;
  const int wr = w >> 2;        // 0..1 : M half
  const int wcn = w & 3;        // 0..3 : N quarter
  const int col = lane & 15, quad = lane >> 4;
  const long m0 = (long)blockIdx.y * 256, n0 = (long)blockIdx.x * 256;

  floatx4 acc[8][4] = {};
  const int nt = K >> 6;

  // stage K-tile t into buffer buf: 8 gld16/thread (4 A-chunks + 4 B-chunks)
  auto stage = [&](int buf, int t) {
    const long kk = (long)t << 6;
#pragma unroll
    for (int i = 0; i < 4; ++i) {
      const int cj = i * 512 + tid;        // chunk id 0..2047 (row = cj>>3, slot = cj&7)
      const int row = cj >> 3;
      const int sc = (cj & 7) ^ (row & 7); // swizzled global source chunk
      gld16(A + (m0 + row) * lda + kk + sc * 8, ldsA[buf] + cj * 8);
      gld16(Bt + (n0 + row) * ldb + kk + sc * 8, ldsB[buf] + cj * 8);
    }
  };

  stage(0, 0);
  for (int t = 0; t < nt; ++t) {
    const int cur = t & 1;
    stage(cur ^ 1, (t + 1 == nt) ? 0 : t + 1);  // wrap keeps vmcnt uniform; harmless re-load
    __builtin_amdgcn_sched_barrier(0);
    asm volatile("s_waitcnt vmcnt(8)" ::: "memory");  // own cur-tile 8 done; next 8 in flight
    __builtin_amdgcn_sched_barrier(0);
    __builtin_amdgcn_s_barrier();                     // all waves' cur-tile loads done
    __builtin_amdgcn_sched_barrier(0);

#pragma unroll
    for (int ks = 0; ks < 2; ++ks) {
      bf16x8 af[8], bf[4];
#pragma unroll
      for (int m = 0; m < 8; ++m) {
        const int ra = wr * 128 + m * 16 + col;
        af[m] = *(const bf16x8*)(ldsA[cur] + ra * 64 + (((ks << 2) | quad) ^ (ra & 7)) * 8);
      }
#pragma unroll
      for (int n = 0; n < 4; ++n) {
        const int rb = wcn * 64 + n * 16 + col;
        bf[n] = *(const bf16x8*)(ldsB[cur] + rb * 64 + (((ks << 2) | quad) ^ (rb & 7)) * 8);
      }
      __builtin_amdgcn_s_setprio(1);
#pragma unroll
      for (int m = 0; m < 8; ++m)
#pragma unroll
        for (int n = 0; n < 4; ++n)
          acc[m][n] = __builtin_amdgcn_mfma_f32_16x16x32_bf16(af[m], bf[n], acc[m][n], 0, 0, 0);
      __builtin_amdgcn_s_setprio(0);
    }

    __builtin_amdgcn_sched_barrier(0);
    __builtin_amdgcn_s_barrier();  // all waves done reading cur before it is restaged
    __builtin_amdgcn_sched_barrier(0);
  }

#pragma unroll
  for (int m = 0; m < 8; ++m) {
#pragma unroll
    for (int n = 0; n < 4; ++n) {
      const long row0 = m0 + wr * 128 + m * 16 + quad * 4;
      const long cc = n0 + wcn * 64 + n * 16 + col;
      const float bvv = bias ? bias[cc] : 0.f;
#pragma unroll
      for (int r = 0; r < 4; ++r) {
        const float v = acc[m][n][r] + bvv;
        if (mode == 0)      ((bf16_t*)Cv)[(row0 + r) * ldc + cc] = (bf16_t)v;
        else if (mode == 1) ((float*)Cv)[(row0 + r) * ldc + cc] = v;
        else {
          if (cc < 3584)      ((bf16_t*)Cv)[(row0 + r) * ldc + cc] = (bf16_t)v;
          else if (cc < 4096) ((bf16_t*)Cv2)[(row0 + r) * 512 + (cc - 3584)] = (bf16_t)v;
          else ((bf16_t*)Cv2)[1048576 + (cc - 4096) * (long)T_SEQ + (row0 + r)] = (bf16_t)v;
        }
      }
    }
  }
}

// ---------------- GEMM (fallback): C[M][N] = A[M][K] @ B[K][N] (+fp32 bias) ----------------
__global__ __launch_bounds__(256) void gemm_nt_k(
    const void* A, long lda, const void* B, long ldb,
    const float* bias, void* Cv, long ldc,
    int K, int aMode, int bMode, int transC, int c32, const int* flag) {
  __shared__ alignas(16) bf16_t ldsA[128 * 32];
  __shared__ alignas(16) unsigned int ldsB32[128 * 16];
  const int f = *flag;
  const bool aF32 = aMode && (f > 32);
  const bool bF32 = bMode && (f > 32);
  const int tid = threadIdx.x;
  const int lane = tid & 63;
  const int w = tid >> 6;
  const int wr = w >> 1, wc = w & 1;
  const int col = lane & 15, quad = lane >> 4;
  const long m0 = (long)blockIdx.y * 128, n0 = (long)blockIdx.x * 128;

  const int ar1 = tid >> 2, ak = (tid & 3) * 8;
  const int ar2 = 64 + ar1;
  const int kk = (tid >> 4) * 2;
  const int nn = (tid & 15) * 8;
  const int kp = kk >> 1;

  floatx4 acc[4][4] = {};

  for (int k0 = 0; k0 < K; k0 += 32) {
    const bf16x8 a1 = ld8(A, (m0 + ar1) * lda + k0 + ak, aF32);
    const bf16x8 a2 = ld8(A, (m0 + ar2) * lda + k0 + ak, aF32);
    const bf16x8 b0 = ld8(B, (long)(k0 + kk) * ldb + n0 + nn, bF32);
    const bf16x8 b1 = ld8(B, (long)(k0 + kk + 1) * ldb + n0 + nn, bF32);
    __syncthreads();
    *(bf16x8*)(ldsA + ar1 * 32 + ak) = a1;
    *(bf16x8*)(ldsA + ar2 * 32 + ak) = a2;
#pragma unroll
    for (int j = 0; j < 8; ++j) {
      const int n = nn + j;
      const int pk = ((((kp >> 2) ^ ((n >> 3) & 3)) << 2) | (kp & 3));
      union { struct { bf16_t lo, hi; } s; unsigned int u; } cv;
      cv.s.lo = b0[j];
      cv.s.hi = b1[j];
      ldsB32[n * 16 + pk] = cv.u;
    }
    __syncthreads();
    bf16x8 af[4], bfv[4];
#pragma unroll
    for (int i = 0; i < 4; ++i)
      af[i] = *(const bf16x8*)(ldsA + (wr * 64 + i * 16 + col) * 32 + quad * 8);
#pragma unroll
    for (int j = 0; j < 4; ++j) {
      const int n = wc * 64 + j * 16 + col;
      const int blk = quad ^ ((n >> 3) & 3);
      bfv[j] = *(const bf16x8*)((const bf16_t*)(ldsB32 + n * 16 + blk * 4));
    }
#pragma unroll
    for (int i = 0; i < 4; ++i)
#pragma unroll
      for (int jj = 0; jj < 4; ++jj)
        acc[i][jj] = __builtin_amdgcn_mfma_f32_16x16x32_bf16(af[i], bfv[jj], acc[i][jj], 0, 0, 0);
  }

#pragma unroll
  for (int i = 0; i < 4; ++i) {
#pragma unroll
    for (int j = 0; j < 4; ++j) {
      const long row0 = m0 + wr * 64 + i * 16 + quad * 4;
      const long cc = n0 + wc * 64 + j * 16 + col;
      const float bvv = bias ? bias[cc] : 0.f;
#pragma unroll
      for (int r = 0; r < 4; ++r) {
        const float v = acc[i][j][r] + bvv;
        if (transC)   ((bf16_t*)Cv)[cc * ldc + (row0 + r)] = (bf16_t)v;
        else if (c32) ((float*)Cv)[(row0 + r) * ldc + cc] = v;
        else          ((bf16_t*)Cv)[(row0 + r) * ldc + cc] = (bf16_t)v;
      }
    }
  }
}

// ---------------- RoPE in-place: buf [T][ld] bf16 ----------------
__global__ void rope_k(bf16_t* buf, const int* __restrict__ pos, long ld, int nheads) {
  const int idx = blockIdx.x * 256 + threadIdx.x;
  const int total = T_SEQ * nheads * 64;
  if (idx >= total) return;
  const int d = idx & 63;
  const int th = idx >> 6;
  const int h = th % nheads;
  const int t = th / nheads;
  const float inv = exp2f((float)d * (-19.931568569324174f / 64.f));
  const float ang = (float)pos[t] * inv;
  float sn, cs;
  __sincosf(ang, &sn, &cs);
  bf16_t* p = buf + (long)t * ld + h * HD + d;
  const float x1 = (float)p[0];
  const float x2 = (float)p[64];
  p[0] = (bf16_t)(x1 * cs - x2 * sn);
  p[64] = (bf16_t)(x2 * cs + x1 * sn);
}

// ---------------- flash attention v5: 4 waves x 32 q-rows ----------------
// grid (16, 28), block 256 = 4 waves x 32 q-rows (2 subtiles of 16), s-tile = 64.
// Staging/pipeline: global_load_lds 16B, counted vmcnt(8), raw s_barrier, XOR-swizzled
// chunks; log2-domain softmax, per-16-row group max, ones-MFMA row-sum, defer-max THR=12.
__global__ __launch_bounds__(256, 2) void attn5_k(
    const bf16_t* __restrict__ q, long qs,
    const bf16_t* __restrict__ k, long ks,
    const bf16_t* __restrict__ vt,  // [512][2048] (hkv*128+d major, s minor)
    bf16_t* __restrict__ out, long os) {
  __shared__ alignas(16) bf16_t ldsK[2][64 * 128];  // 16KB x2
  __shared__ alignas(16) bf16_t ldsV[2][128 * 64];  // 16KB x2
  __shared__ alignas(16) bf16_t pbuf[4][32 * 64];   // per-wave P (32 rows), 4KB/wave

  const int h = blockIdx.y;
  const long hkvHD = (long)(h / GQA) * HD;
  const int tid = threadIdx.x;
  const int lane = tid & 63;
  const int w = tid >> 6;
  const int col = lane & 15, quad = lane >> 4;
  const int t0 = blockIdx.x * 128 + w * 32;

  auto stage = [&](int buf, int t) {
    const long s0 = (long)t * 64;
#pragma unroll
    for (int i = 0; i < 4; ++i) {
      const int J = i * 256 + tid;
      {  // K: 64 rows x 16 chunks
        const int row = J >> 4;
        const int cs = (J & 15) ^ (row & 7);
        gld16(k + (s0 + row) * ks + hkvHD + cs * 8, &ldsK[buf][J * 8]);
      }
      {  // V: 128 rows x 8 chunks
        const int row = J >> 3;
        const int cs = (J & 7) ^ (row & 7);
        gld16(vt + (hkvHD + row) * T_SEQ + s0 + cs * 8, &ldsV[buf][J * 8]);
      }
    }
  };

  bf16x8 aq[2][4];
#pragma unroll
  for (int sub = 0; sub < 2; ++sub) {
    const bf16_t* qp = q + (long)(t0 + sub * 16 + col) * qs + h * HD + quad * 8;
#pragma unroll
    for (int c = 0; c < 4; ++c) {
      aq[sub][c] = *(const bf16x8*)(qp + c * 32);
#pragma unroll
      for (int e = 0; e < 8; ++e)
        aq[sub][c][e] = (bf16_t)((float)aq[sub][c][e] * QSCALE_LOG2);
    }
  }

  bf16x8 ones;
#pragma unroll
  for (int e = 0; e < 8; ++e) ones[e] = (bf16_t)1.0f;

  floatx4 O[2][8] = {};
  float m_w[2] = {-1e30f, -1e30f};
  float l_i[2][4] = {};

  stage(0, 0);
  for (int t = 0; t < 32; ++t) {
    const int cur = t & 1;
    stage(cur ^ 1, (t + 1) & 31);
    __builtin_amdgcn_sched_barrier(0);
    asm volatile("s_waitcnt vmcnt(8)" ::: "memory");
    __builtin_amdgcn_sched_barrier(0);
    __builtin_amdgcn_s_barrier();
    __builtin_amdgcn_sched_barrier(0);

    // ---- S = q . K^T (log2 units); bk shared across both q-subtiles ----
    floatx4 S[2][4] = {};
    __builtin_amdgcn_s_setprio(1);
#pragma unroll
    for (int nt = 0; nt < 4; ++nt) {
      const int row = nt * 16 + col;
#pragma unroll
      for (int c = 0; c < 4; ++c) {
        const int cs = (c * 4 + quad) ^ (row & 7);
        const bf16x8 bk = *(const bf16x8*)(&ldsK[cur][row * 128 + cs * 8]);
        S[0][nt] = __builtin_amdgcn_mfma_f32_16x16x32_bf16(aq[0][c], bk, S[0][nt], 0, 0, 0);
        S[1][nt] = __builtin_amdgcn_mfma_f32_16x16x32_bf16(aq[1][c], bk, S[1][nt], 0, 0, 0);
      }
    }
    __builtin_amdgcn_s_setprio(0);

    // ---- per-subtile group max + defer-max rescale (wave-uniform branch) ----
#pragma unroll
    for (int sub = 0; sub < 2; ++sub) {
      float mx = S[sub][0][0];
#pragma unroll
      for (int nt = 0; nt < 4; ++nt)
#pragma unroll
        for (int r = 0; r < 4; ++r) mx = fmaxf(mx, S[sub][nt][r]);
#pragma unroll
      for (int off = 1; off < 64; off <<= 1)
        mx = fmaxf(mx, __shfl_xor(mx, off, 64));
      if (mx > m_w[sub] + 12.0f) {
        const float alpha = exp2f(m_w[sub] - mx);
        m_w[sub] = mx;
#pragma unroll
        for (int r = 0; r < 4; ++r) l_i[sub][r] *= alpha;
#pragma unroll
        for (int dt = 0; dt < 8; ++dt)
#pragma unroll
          for (int r = 0; r < 4; ++r) O[sub][dt][r] *= alpha;
      }
    }

    // ---- P = exp2(S - m), store to swizzled pbuf ----
#pragma unroll
    for (int sub = 0; sub < 2; ++sub)
#pragma unroll
      for (int r = 0; r < 4; ++r) {
        const int mrow = sub * 16 + quad * 4 + r;
#pragma unroll
        for (int nt = 0; nt < 4; ++nt) {
          const float p = exp2f(S[sub][nt][r] - m_w[sub]);
          const int cs = (nt * 2 + (col >> 3)) ^ (mrow & 7);
          pbuf[w][mrow * 64 + cs * 8 + (col & 7)] = (bf16_t)p;
        }
      }

    // ---- O += P @ V ; bv shared across subtiles; row-sum via mfma(pa, ones) ----
    floatx4 Ssum[2] = {};
    __builtin_amdgcn_s_setprio(1);
#pragma unroll
    for (int kb = 0; kb < 2; ++kb) {
      const int csp = (kb * 4 + quad) ^ (col & 7);
      const bf16x8 pa0 = *(const bf16x8*)(&pbuf[w][(col) * 64 + csp * 8]);
      const bf16x8 pa1 = *(const bf16x8*)(&pbuf[w][(16 + col) * 64 + csp * 8]);
      Ssum[0] = __builtin_amdgcn_mfma_f32_16x16x32_bf16(pa0, ones, Ssum[0], 0, 0, 0);
      Ssum[1] = __builtin_amdgcn_mfma_f32_16x16x32_bf16(pa1, ones, Ssum[1], 0, 0, 0);
#pragma unroll
      for (int dt = 0; dt < 8; ++dt) {
        const int vrow = dt * 16 + col;
        const bf16x8 bv = *(const bf16x8*)(&ldsV[cur][vrow * 64 + csp * 8]);
        O[0][dt] = __builtin_amdgcn_mfma_f32_16x16x32_bf16(pa0, bv, O[0][dt], 0, 0, 0);
        O[1][dt] = __builtin_amdgcn_mfma_f32_16x16x32_bf16(pa1, bv, O[1][dt], 0, 0, 0);
      }
    }
    __builtin_amdgcn_s_setprio(0);
#pragma unroll
    for (int sub = 0; sub < 2; ++sub)
#pragma unroll
      for (int r = 0; r < 4; ++r) l_i[sub][r] += Ssum[sub][r];

    __builtin_amdgcn_sched_barrier(0);
    __builtin_amdgcn_s_barrier();
    __builtin_amdgcn_sched_barrier(0);
  }

#pragma unroll
  for (int sub = 0; sub < 2; ++sub) {
#pragma unroll
    for (int r = 0; r < 4; ++r) l_i[sub][r] = 1.f / l_i[sub][r];
#pragma unroll
    for (int dt = 0; dt < 8; ++dt) {
#pragma unroll
      for (int r = 0; r < 4; ++r) {
        const long trow = t0 + sub * 16 + quad * 4 + r;
        out[trow * os + h * HD + dt * 16 + col] = (bf16_t)(O[sub][dt][r] * l_i[sub][r]);
      }
    }
  }
}

extern "C" void kernel_launch(void* const* d_in, const int* in_sizes, int n_in,
                              void* d_out_v, int out_size, void* d_ws, size_t ws_size,
                              hipStream_t stream) {
  const int* pos = (const int*)d_in[0];
  const float* hidden = (const float*)d_in[1];
  const float* wq = (const float*)d_in[2];
  const float* bq = (const float*)d_in[3];
  const float* wk = (const float*)d_in[4];
  const float* bk = (const float*)d_in[5];
  const float* wv = (const float*)d_in[6];
  const float* bv = (const float*)d_in[7];
  const float* wo = (const float*)d_in[8];

  bf16_t* qbuf = (bf16_t*)d_out_v;                          // lower half of d_out (bf16 q)
  bf16_t* attn_hi = (bf16_t*)d_out_v + (size_t)T_SEQ * HID; // upper half (scratch / fallback)
  float* outf = (float*)d_out_v;

  char* ws = (char*)d_ws;
  const size_t NEED = 51904516;

  if (ws_size >= NEED) {
    // ---- fast path: bf16 operands, weights pre-transposed; QKV fused GEMM ----
    bf16_t* hbf  = (bf16_t*)ws;                  // [2048][3584]  (later: attn out)
    bf16_t* wqbt = (bf16_t*)(ws + 14680064);     // [3584][3584] = wq^T (later: wo^T)
    bf16_t* wkbt = (bf16_t*)(ws + 40370176);     // [512][3584]  = wk^T (contig after wqbt)
    bf16_t* wvbt = (bf16_t*)(ws + 44040192);     // [512][3584]  = wv^T (contig after wkbt)
    bf16_t* kbuf = (bf16_t*)(ws + 47710208);     // [2048][512]
    bf16_t* vt   = (bf16_t*)(ws + 49807360);     // [512][2048]  (= kbuf + 1048576 elems)
    bf16_t* wobt = wqbt;
    bf16_t* attnb = hbf;
    float* bqkv = (float*)attn_hi;               // 4608 fp32 concat bias in d_out upper half

    hipMemcpyAsync(bqkv, bq, 3584 * sizeof(float), hipMemcpyDeviceToDevice, stream);
    hipMemcpyAsync(bqkv + 3584, bk, 512 * sizeof(float), hipMemcpyDeviceToDevice, stream);
    hipMemcpyAsync(bqkv + 4096, bv, 512 * sizeof(float), hipMemcpyDeviceToDevice, stream);

    conv_bf_k<<<3584, 256, 0, stream>>>(hidden, hbf, (long)T_SEQ * HID);
    tconv_k<<<dim3(56, 56), 256, 0, stream>>>(wq, wqbt, HID, HID);
    tconv_k<<<dim3(8, 56), 256, 0, stream>>>(wk, wkbt, 512, HID);
    tconv_k<<<dim3(8, 56), 256, 0, stream>>>(wv, wvbt, 512, HID);

    // fused Q/K/V projection: Bt = [wq^T; wk^T; wv^T] (4608 rows), one launch
    gemm8_k<<<dim3(18, 8), 512, 0, stream>>>(hbf, HID, wqbt, HID, bqkv, qbuf, HID,
                                             HID, 3, kbuf);

    rope_k<<<(T_SEQ * NH * 64) / 256, 256, 0, stream>>>(qbuf, pos, HID, NH);
    rope_k<<<(T_SEQ * NKV * 64) / 256, 256, 0, stream>>>(kbuf, pos, 512, NKV);

    attn5_k<<<dim3(16, 28), 256, 0, stream>>>(qbuf, HID, kbuf, 512, vt, attnb, HID);

    // wo^T (reuses wq^T region, dead after QKV-GEMM)
    tconv_k<<<dim3(56, 56), 256, 0, stream>>>(wo, wobt, HID, HID);

    gemm8_k<<<dim3(14, 8), 512, 0, stream>>>(attnb, HID, wobt, HID, nullptr,
                                             outf, HID, HID, 1, nullptr);
  } else {
    // ---- fallback: fp32-reading path (ws >= 4,194,308) ----
    bf16_t* kbuf = (bf16_t*)ws;
    bf16_t* vt = (bf16_t*)(ws + 2097152);
    bf16_t* acopy = (bf16_t*)ws;
    int* flag = (int*)(ws + 4194304);

    hipMemsetAsync(flag, 64, 4, stream);  // 0x40404040 > 32 -> fp32 inputs

    gemm_nt_k<<<dim3(28, 16), 256, 0, stream>>>(hidden, HID, wq, HID, bq, qbuf, HID,
                                                HID, 1, 1, 0, 0, flag);
    gemm_nt_k<<<dim3(4, 16), 256, 0, stream>>>(hidden, HID, wk, 512, bk, kbuf, 512,
                                               HID, 1, 1, 0, 0, flag);
    gemm_nt_k<<<dim3(4, 16), 256, 0, stream>>>(hidden, HID, wv, 512, bv, vt, T_SEQ,
                                               HID, 1, 1, 1, 0, flag);

    rope_k<<<(T_SEQ * NH * 64) / 256, 256, 0, stream>>>(qbuf, pos, HID, NH);
    rope_k<<<(T_SEQ * NKV * 64) / 256, 256, 0, stream>>>(kbuf, pos, 512, NKV);

    attn5_k<<<dim3(16, 28), 256, 0, stream>>>(qbuf, HID, kbuf, 512, vt, attn_hi, HID);

    hipMemcpyAsync(acopy, attn_hi + (size_t)1536 * HID, (size_t)512 * HID * 2,
                   hipMemcpyDeviceToDevice, stream);
    gemm_nt_k<<<dim3(28, 8), 256, 0, stream>>>(attn_hi, HID, wo, HID, nullptr,
                                               outf, HID, HID, 0, 1, 0, 1, flag);
    gemm_nt_k<<<dim3(28, 4), 256, 0, stream>>>(attn_hi + (size_t)1024 * HID, HID, wo, HID,
                                               nullptr, outf + (size_t)1024 * HID, HID,
                                               HID, 0, 1, 0, 1, flag);
    gemm_nt_k<<<dim3(28, 4), 256, 0, stream>>>(acopy, HID, wo, HID,
                                               nullptr, outf + (size_t)1536 * HID, HID,
                                               HID, 0, 1, 0, 1, flag);
  }
}

// Round 8
// 520.311 us; speedup vs baseline: 1.1127x; 1.1127x over previous
//
#include <hip/hip_runtime.h>

typedef __bf16 bf16_t;
typedef __attribute__((ext_vector_type(8))) __bf16 bf16x8;
typedef __attribute__((ext_vector_type(4))) float floatx4;

#define T_SEQ 2048
#define HID 3584
#define NH 28
#define NKV 4
#define HD 128
#define GQA 7
#define SCALE_F 0.08838834764831845f
// SCALE_F * log2(e): QK^T directly in log2 domain (exp2 = 1 instr)
#define QSCALE_LOG2 0.1275179100693744f

// ---------------- fp32 -> bf16 conversion (n % 2048 == 0) ----------------
__global__ void conv_bf_k(const float* __restrict__ src, bf16_t* __restrict__ dst, long n) {
  const long i = ((long)blockIdx.x * 256 + threadIdx.x) * 8;
  if (i >= n) return;
  const floatx4 a = *(const floatx4*)(src + i);
  const floatx4 b = *(const floatx4*)(src + i + 4);
  bf16x8 r;
  r[0] = (bf16_t)a[0]; r[1] = (bf16_t)a[1]; r[2] = (bf16_t)a[2]; r[3] = (bf16_t)a[3];
  r[4] = (bf16_t)b[0]; r[5] = (bf16_t)b[1]; r[6] = (bf16_t)b[2]; r[7] = (bf16_t)b[3];
  *(bf16x8*)(dst + i) = r;
}

// ---------------- transposing fp32 -> bf16: dst[N][K] = (bf16)src[K][N]^T ----------------
__global__ __launch_bounds__(256) void tconv_k(const float* __restrict__ src,
                                               bf16_t* __restrict__ dst, long N, long K) {
  __shared__ alignas(16) bf16_t t[64][72];
  const long k0 = (long)blockIdx.y * 64, n0 = (long)blockIdx.x * 64;
  const int tid = threadIdx.x;
  const int rr = tid >> 4;
  const int cc = (tid & 15) * 4;
#pragma unroll
  for (int i = 0; i < 4; ++i) {
    const int r = rr + i * 16;
    const floatx4 v = *(const floatx4*)(src + (k0 + r) * N + n0 + cc);
#pragma unroll
    for (int j = 0; j < 4; ++j) t[cc + j][r] = (bf16_t)v[j];
  }
  __syncthreads();
#pragma unroll
  for (int i = 0; i < 2; ++i) {
    const int J = i * 256 + tid;
    const int n = J >> 3, c8 = (J & 7) * 8;
    *(bf16x8*)(dst + (n0 + n) * K + k0 + c8) = *(const bf16x8*)(&t[n][c8]);
  }
}

// load 8 contiguous elements as bf16x8, converting from fp32 if f32 is set
__device__ __forceinline__ bf16x8 ld8(const void* p, long idx, bool f32) {
  if (f32) {
    const float* q = (const float*)p + idx;
    const floatx4 u = *(const floatx4*)q;
    const floatx4 v = *(const floatx4*)(q + 4);
    bf16x8 r;
    r[0] = (bf16_t)u[0]; r[1] = (bf16_t)u[1]; r[2] = (bf16_t)u[2]; r[3] = (bf16_t)u[3];
    r[4] = (bf16_t)v[0]; r[5] = (bf16_t)v[1]; r[6] = (bf16_t)v[2]; r[7] = (bf16_t)v[3];
    return r;
  }
  return *(const bf16x8*)((const bf16_t*)p + idx);
}

__device__ __forceinline__ void gld16(const bf16_t* g, bf16_t* l) {
  __builtin_amdgcn_global_load_lds(
      (const __attribute__((address_space(1))) unsigned int*)(const void*)g,
      (__attribute__((address_space(3))) unsigned int*)(void*)l, 16, 0, 0);
}

// ---------------- GEMM (fast path): C[M][N] = A[M][K] @ Bt[N][K]^T (+fp32 bias) ----------------
// 128x128 tile, BK=64, 256 threads, LDS double-buffered (64KB -> 2 blocks/CU),
// counted vmcnt(8) + raw s_barrier: next K-tile's 8 loads stay in flight across the
// barrier; barrier-pair count halved vs BK=32 (56 vs 112 for K=3584).
// Chunk swizzle (rule #21): rows are 8x16B slots; LDS slot (row,c) holds global chunk
// c ^ (row&7), applied on the per-lane GLOBAL source (dest lane-linear for
// global_load_lds) and on fragment reads: slot = ((ks*4+quad) ^ (ra&7)). ra&7 == col&7,
// so each 8-lane issue group covers all 8 slots -> conflict-free; staging loads remain
// 128B-coalesced (slot permutation within each row).
// mode 0: bf16 C. mode 1: fp32 C. mode 3: fused QKV epilogue (cc<3584 -> Cv bf16
// [row][ldc]; 3584<=cc<4096 -> Cv2[row][512]; cc>=4096 -> Cv2+1048576 transposed
// [cc-4096][T_SEQ]).
__global__ __launch_bounds__(256) void gemm_bt_k(
    const bf16_t* __restrict__ A, long lda,
    const bf16_t* __restrict__ Bt, long ldb,
    const float* __restrict__ bias, void* Cv, long ldc,
    int K, int mode, void* Cv2) {
  __shared__ alignas(16) bf16_t ldsA[2][128 * 64];  // 16KB x2
  __shared__ alignas(16) bf16_t ldsB[2][128 * 64];  // 16KB x2
  const int tid = threadIdx.x;
  const int lane = tid & 63;
  const int w = tid >> 6;
  const int wr = w >> 1, wc = w & 1;
  const int col = lane & 15, quad = lane >> 4;
  const long m0 = (long)blockIdx.y * 128, n0 = (long)blockIdx.x * 128;

  floatx4 acc[4][4] = {};
  const int nt = K >> 6;

  // stage K-tile t: 1024 chunks per matrix (128 rows x 8 slots), 4+4 gld16/thread
  auto stage = [&](int buf, int t) {
    const long kk = (long)t << 6;
#pragma unroll
    for (int i = 0; i < 4; ++i) {
      const int cj = i * 256 + tid;         // chunk id: row = cj>>3, slot = cj&7
      const int row = cj >> 3;
      const int sc = (cj & 7) ^ (row & 7);  // swizzled global source chunk
      gld16(A + (m0 + row) * lda + kk + sc * 8, ldsA[buf] + cj * 8);
      gld16(Bt + (n0 + row) * ldb + kk + sc * 8, ldsB[buf] + cj * 8);
    }
  };

  stage(0, 0);
  for (int t = 0; t < nt; ++t) {
    const int cur = t & 1;
    stage(cur ^ 1, (t + 1 == nt) ? 0 : t + 1);  // wrap keeps vmcnt uniform; harmless re-load
    __builtin_amdgcn_sched_barrier(0);
    asm volatile("s_waitcnt vmcnt(8)" ::: "memory");  // own cur-tile 8 done; next 8 in flight
    __builtin_amdgcn_sched_barrier(0);
    __builtin_amdgcn_s_barrier();                     // all waves' cur-tile loads done
    __builtin_amdgcn_sched_barrier(0);

#pragma unroll
    for (int ks = 0; ks < 2; ++ks) {
      bf16x8 af[4], bf[4];
#pragma unroll
      for (int i = 0; i < 4; ++i) {
        const int ra = wr * 64 + i * 16 + col;
        af[i] = *(const bf16x8*)(ldsA[cur] + ra * 64 + (((ks << 2) | quad) ^ (ra & 7)) * 8);
      }
#pragma unroll
      for (int j = 0; j < 4; ++j) {
        const int rb = wc * 64 + j * 16 + col;
        bf[j] = *(const bf16x8*)(ldsB[cur] + rb * 64 + (((ks << 2) | quad) ^ (rb & 7)) * 8);
      }
      __builtin_amdgcn_s_setprio(1);
#pragma unroll
      for (int i = 0; i < 4; ++i)
#pragma unroll
        for (int j = 0; j < 4; ++j)
          acc[i][j] = __builtin_amdgcn_mfma_f32_16x16x32_bf16(af[i], bf[j], acc[i][j], 0, 0, 0);
      __builtin_amdgcn_s_setprio(0);
    }

    __builtin_amdgcn_sched_barrier(0);
    __builtin_amdgcn_s_barrier();  // all waves done reading cur before it is restaged
    __builtin_amdgcn_sched_barrier(0);
  }

#pragma unroll
  for (int i = 0; i < 4; ++i) {
#pragma unroll
    for (int j = 0; j < 4; ++j) {
      const long row0 = m0 + wr * 64 + i * 16 + quad * 4;
      const long cc = n0 + wc * 64 + j * 16 + col;
      const float bvv = bias ? bias[cc] : 0.f;
#pragma unroll
      for (int r = 0; r < 4; ++r) {
        const float v = acc[i][j][r] + bvv;
        if (mode == 0)      ((bf16_t*)Cv)[(row0 + r) * ldc + cc] = (bf16_t)v;
        else if (mode == 1) ((float*)Cv)[(row0 + r) * ldc + cc] = v;
        else {
          if (cc < 3584)      ((bf16_t*)Cv)[(row0 + r) * ldc + cc] = (bf16_t)v;
          else if (cc < 4096) ((bf16_t*)Cv2)[(row0 + r) * 512 + (cc - 3584)] = (bf16_t)v;
          else ((bf16_t*)Cv2)[1048576 + (cc - 4096) * (long)T_SEQ + (row0 + r)] = (bf16_t)v;
        }
      }
    }
  }
}

// ---------------- GEMM (fallback): C[M][N] = A[M][K] @ B[K][N] (+fp32 bias) ----------------
__global__ __launch_bounds__(256) void gemm_nt_k(
    const void* A, long lda, const void* B, long ldb,
    const float* bias, void* Cv, long ldc,
    int K, int aMode, int bMode, int transC, int c32, const int* flag) {
  __shared__ alignas(16) bf16_t ldsA[128 * 32];
  __shared__ alignas(16) unsigned int ldsB32[128 * 16];
  const int f = *flag;
  const bool aF32 = aMode && (f > 32);
  const bool bF32 = bMode && (f > 32);
  const int tid = threadIdx.x;
  const int lane = tid & 63;
  const int w = tid >> 6;
  const int wr = w >> 1, wc = w & 1;
  const int col = lane & 15, quad = lane >> 4;
  const long m0 = (long)blockIdx.y * 128, n0 = (long)blockIdx.x * 128;

  const int ar1 = tid >> 2, ak = (tid & 3) * 8;
  const int ar2 = 64 + ar1;
  const int kk = (tid >> 4) * 2;
  const int nn = (tid & 15) * 8;
  const int kp = kk >> 1;

  floatx4 acc[4][4] = {};

  for (int k0 = 0; k0 < K; k0 += 32) {
    const bf16x8 a1 = ld8(A, (m0 + ar1) * lda + k0 + ak, aF32);
    const bf16x8 a2 = ld8(A, (m0 + ar2) * lda + k0 + ak, aF32);
    const bf16x8 b0 = ld8(B, (long)(k0 + kk) * ldb + n0 + nn, bF32);
    const bf16x8 b1 = ld8(B, (long)(k0 + kk + 1) * ldb + n0 + nn, bF32);
    __syncthreads();
    *(bf16x8*)(ldsA + ar1 * 32 + ak) = a1;
    *(bf16x8*)(ldsA + ar2 * 32 + ak) = a2;
#pragma unroll
    for (int j = 0; j < 8; ++j) {
      const int n = nn + j;
      const int pk = ((((kp >> 2) ^ ((n >> 3) & 3)) << 2) | (kp & 3));
      union { struct { bf16_t lo, hi; } s; unsigned int u; } cv;
      cv.s.lo = b0[j];
      cv.s.hi = b1[j];
      ldsB32[n * 16 + pk] = cv.u;
    }
    __syncthreads();
    bf16x8 af[4], bfv[4];
#pragma unroll
    for (int i = 0; i < 4; ++i)
      af[i] = *(const bf16x8*)(ldsA + (wr * 64 + i * 16 + col) * 32 + quad * 8);
#pragma unroll
    for (int j = 0; j < 4; ++j) {
      const int n = wc * 64 + j * 16 + col;
      const int blk = quad ^ ((n >> 3) & 3);
      bfv[j] = *(const bf16x8*)((const bf16_t*)(ldsB32 + n * 16 + blk * 4));
    }
#pragma unroll
    for (int i = 0; i < 4; ++i)
#pragma unroll
      for (int jj = 0; jj < 4; ++jj)
        acc[i][jj] = __builtin_amdgcn_mfma_f32_16x16x32_bf16(af[i], bfv[jj], acc[i][jj], 0, 0, 0);
  }

#pragma unroll
  for (int i = 0; i < 4; ++i) {
#pragma unroll
    for (int j = 0; j < 4; ++j) {
      const long row0 = m0 + wr * 64 + i * 16 + quad * 4;
      const long cc = n0 + wc * 64 + j * 16 + col;
      const float bvv = bias ? bias[cc] : 0.f;
#pragma unroll
      for (int r = 0; r < 4; ++r) {
        const float v = acc[i][j][r] + bvv;
        if (transC)   ((bf16_t*)Cv)[cc * ldc + (row0 + r)] = (bf16_t)v;
        else if (c32) ((float*)Cv)[(row0 + r) * ldc + cc] = v;
        else          ((bf16_t*)Cv)[(row0 + r) * ldc + cc] = (bf16_t)v;
      }
    }
  }
}

// ---------------- RoPE in-place: buf [T][ld] bf16 ----------------
__global__ void rope_k(bf16_t* buf, const int* __restrict__ pos, long ld, int nheads) {
  const int idx = blockIdx.x * 256 + threadIdx.x;
  const int total = T_SEQ * nheads * 64;
  if (idx >= total) return;
  const int d = idx & 63;
  const int th = idx >> 6;
  const int h = th % nheads;
  const int t = th / nheads;
  const float inv = exp2f((float)d * (-19.931568569324174f / 64.f));
  const float ang = (float)pos[t] * inv;
  float sn, cs;
  __sincosf(ang, &sn, &cs);
  bf16_t* p = buf + (long)t * ld + h * HD + d;
  const float x1 = (float)p[0];
  const float x2 = (float)p[64];
  p[0] = (bf16_t)(x1 * cs - x2 * sn);
  p[64] = (bf16_t)(x2 * cs + x1 * sn);
}

// ---------------- flash attention v5: 4 waves x 32 q-rows ----------------
// grid (16, 28), block 256 = 4 waves x 32 q-rows (2 subtiles of 16), s-tile = 64.
// Staging/pipeline: global_load_lds 16B, counted vmcnt(8), raw s_barrier, XOR-swizzled
// chunks; log2-domain softmax, per-16-row group max, ones-MFMA row-sum, defer-max THR=12.
__global__ __launch_bounds__(256, 2) void attn5_k(
    const bf16_t* __restrict__ q, long qs,
    const bf16_t* __restrict__ k, long ks,
    const bf16_t* __restrict__ vt,  // [512][2048] (hkv*128+d major, s minor)
    bf16_t* __restrict__ out, long os) {
  __shared__ alignas(16) bf16_t ldsK[2][64 * 128];  // 16KB x2
  __shared__ alignas(16) bf16_t ldsV[2][128 * 64];  // 16KB x2
  __shared__ alignas(16) bf16_t pbuf[4][32 * 64];   // per-wave P (32 rows), 4KB/wave

  const int h = blockIdx.y;
  const long hkvHD = (long)(h / GQA) * HD;
  const int tid = threadIdx.x;
  const int lane = tid & 63;
  const int w = tid >> 6;
  const int col = lane & 15, quad = lane >> 4;
  const int t0 = blockIdx.x * 128 + w * 32;

  auto stage = [&](int buf, int t) {
    const long s0 = (long)t * 64;
#pragma unroll
    for (int i = 0; i < 4; ++i) {
      const int J = i * 256 + tid;
      {  // K: 64 rows x 16 chunks
        const int row = J >> 4;
        const int cs = (J & 15) ^ (row & 7);
        gld16(k + (s0 + row) * ks + hkvHD + cs * 8, &ldsK[buf][J * 8]);
      }
      {  // V: 128 rows x 8 chunks
        const int row = J >> 3;
        const int cs = (J & 7) ^ (row & 7);
        gld16(vt + (hkvHD + row) * T_SEQ + s0 + cs * 8, &ldsV[buf][J * 8]);
      }
    }
  };

  bf16x8 aq[2][4];
#pragma unroll
  for (int sub = 0; sub < 2; ++sub) {
    const bf16_t* qp = q + (long)(t0 + sub * 16 + col) * qs + h * HD + quad * 8;
#pragma unroll
    for (int c = 0; c < 4; ++c) {
      aq[sub][c] = *(const bf16x8*)(qp + c * 32);
#pragma unroll
      for (int e = 0; e < 8; ++e)
        aq[sub][c][e] = (bf16_t)((float)aq[sub][c][e] * QSCALE_LOG2);
    }
  }

  bf16x8 ones;
#pragma unroll
  for (int e = 0; e < 8; ++e) ones[e] = (bf16_t)1.0f;

  floatx4 O[2][8] = {};
  float m_w[2] = {-1e30f, -1e30f};
  float l_i[2][4] = {};

  stage(0, 0);
  for (int t = 0; t < 32; ++t) {
    const int cur = t & 1;
    stage(cur ^ 1, (t + 1) & 31);
    __builtin_amdgcn_sched_barrier(0);
    asm volatile("s_waitcnt vmcnt(8)" ::: "memory");
    __builtin_amdgcn_sched_barrier(0);
    __builtin_amdgcn_s_barrier();
    __builtin_amdgcn_sched_barrier(0);

    // ---- S = q . K^T (log2 units); bk shared across both q-subtiles ----
    floatx4 S[2][4] = {};
    __builtin_amdgcn_s_setprio(1);
#pragma unroll
    for (int nt = 0; nt < 4; ++nt) {
      const int row = nt * 16 + col;
#pragma unroll
      for (int c = 0; c < 4; ++c) {
        const int cs = (c * 4 + quad) ^ (row & 7);
        const bf16x8 bk = *(const bf16x8*)(&ldsK[cur][row * 128 + cs * 8]);
        S[0][nt] = __builtin_amdgcn_mfma_f32_16x16x32_bf16(aq[0][c], bk, S[0][nt], 0, 0, 0);
        S[1][nt] = __builtin_amdgcn_mfma_f32_16x16x32_bf16(aq[1][c], bk, S[1][nt], 0, 0, 0);
      }
    }
    __builtin_amdgcn_s_setprio(0);

    // ---- per-subtile group max + defer-max rescale (wave-uniform branch) ----
#pragma unroll
    for (int sub = 0; sub < 2; ++sub) {
      float mx = S[sub][0][0];
#pragma unroll
      for (int nt = 0; nt < 4; ++nt)
#pragma unroll
        for (int r = 0; r < 4; ++r) mx = fmaxf(mx, S[sub][nt][r]);
#pragma unroll
      for (int off = 1; off < 64; off <<= 1)
        mx = fmaxf(mx, __shfl_xor(mx, off, 64));
      if (mx > m_w[sub] + 12.0f) {
        const float alpha = exp2f(m_w[sub] - mx);
        m_w[sub] = mx;
#pragma unroll
        for (int r = 0; r < 4; ++r) l_i[sub][r] *= alpha;
#pragma unroll
        for (int dt = 0; dt < 8; ++dt)
#pragma unroll
          for (int r = 0; r < 4; ++r) O[sub][dt][r] *= alpha;
      }
    }

    // ---- P = exp2(S - m), store to swizzled pbuf ----
#pragma unroll
    for (int sub = 0; sub < 2; ++sub)
#pragma unroll
      for (int r = 0; r < 4; ++r) {
        const int mrow = sub * 16 + quad * 4 + r;
#pragma unroll
        for (int nt = 0; nt < 4; ++nt) {
          const float p = exp2f(S[sub][nt][r] - m_w[sub]);
          const int cs = (nt * 2 + (col >> 3)) ^ (mrow & 7);
          pbuf[w][mrow * 64 + cs * 8 + (col & 7)] = (bf16_t)p;
        }
      }

    // ---- O += P @ V ; bv shared across subtiles; row-sum via mfma(pa, ones) ----
    floatx4 Ssum[2] = {};
    __builtin_amdgcn_s_setprio(1);
#pragma unroll
    for (int kb = 0; kb < 2; ++kb) {
      const int csp = (kb * 4 + quad) ^ (col & 7);
      const bf16x8 pa0 = *(const bf16x8*)(&pbuf[w][(col) * 64 + csp * 8]);
      const bf16x8 pa1 = *(const bf16x8*)(&pbuf[w][(16 + col) * 64 + csp * 8]);
      Ssum[0] = __builtin_amdgcn_mfma_f32_16x16x32_bf16(pa0, ones, Ssum[0], 0, 0, 0);
      Ssum[1] = __builtin_amdgcn_mfma_f32_16x16x32_bf16(pa1, ones, Ssum[1], 0, 0, 0);
#pragma unroll
      for (int dt = 0; dt < 8; ++dt) {
        const int vrow = dt * 16 + col;
        const bf16x8 bv = *(const bf16x8*)(&ldsV[cur][vrow * 64 + csp * 8]);
        O[0][dt] = __builtin_amdgcn_mfma_f32_16x16x32_bf16(pa0, bv, O[0][dt], 0, 0, 0);
        O[1][dt] = __builtin_amdgcn_mfma_f32_16x16x32_bf16(pa1, bv, O[1][dt], 0, 0, 0);
      }
    }
    __builtin_amdgcn_s_setprio(0);
#pragma unroll
    for (int sub = 0; sub < 2; ++sub)
#pragma unroll
      for (int r = 0; r < 4; ++r) l_i[sub][r] += Ssum[sub][r];

    __builtin_amdgcn_sched_barrier(0);
    __builtin_amdgcn_s_barrier();
    __builtin_amdgcn_sched_barrier(0);
  }

#pragma unroll
  for (int sub = 0; sub < 2; ++sub) {
#pragma unroll
    for (int r = 0; r < 4; ++r) l_i[sub][r] = 1.f / l_i[sub][r];
#pragma unroll
    for (int dt = 0; dt < 8; ++dt) {
#pragma unroll
      for (int r = 0; r < 4; ++r) {
        const long trow = t0 + sub * 16 + quad * 4 + r;
        out[trow * os + h * HD + dt * 16 + col] = (bf16_t)(O[sub][dt][r] * l_i[sub][r]);
      }
    }
  }
}

extern "C" void kernel_launch(void* const* d_in, const int* in_sizes, int n_in,
                              void* d_out_v, int out_size, void* d_ws, size_t ws_size,
                              hipStream_t stream) {
  const int* pos = (const int*)d_in[0];
  const float* hidden = (const float*)d_in[1];
  const float* wq = (const float*)d_in[2];
  const float* bq = (const float*)d_in[3];
  const float* wk = (const float*)d_in[4];
  const float* bk = (const float*)d_in[5];
  const float* wv = (const float*)d_in[6];
  const float* bv = (const float*)d_in[7];
  const float* wo = (const float*)d_in[8];

  bf16_t* qbuf = (bf16_t*)d_out_v;                          // lower half of d_out (bf16 q)
  bf16_t* attn_hi = (bf16_t*)d_out_v + (size_t)T_SEQ * HID; // upper half (scratch / fallback)
  float* outf = (float*)d_out_v;

  char* ws = (char*)d_ws;
  const size_t NEED = 51904516;

  if (ws_size >= NEED) {
    // ---- fast path: bf16 operands, weights pre-transposed; QKV fused GEMM ----
    bf16_t* hbf  = (bf16_t*)ws;                  // [2048][3584]  (later: attn out)
    bf16_t* wqbt = (bf16_t*)(ws + 14680064);     // [3584][3584] = wq^T (later: wo^T)
    bf16_t* wkbt = (bf16_t*)(ws + 40370176);     // [512][3584]  = wk^T (contig after wqbt)
    bf16_t* wvbt = (bf16_t*)(ws + 44040192);     // [512][3584]  = wv^T (contig after wkbt)
    bf16_t* kbuf = (bf16_t*)(ws + 47710208);     // [2048][512]
    bf16_t* vt   = (bf16_t*)(ws + 49807360);     // [512][2048]  (= kbuf + 1048576 elems)
    bf16_t* wobt = wqbt;
    bf16_t* attnb = hbf;
    float* bqkv = (float*)attn_hi;               // 4608 fp32 concat bias in d_out upper half

    hipMemcpyAsync(bqkv, bq, 3584 * sizeof(float), hipMemcpyDeviceToDevice, stream);
    hipMemcpyAsync(bqkv + 3584, bk, 512 * sizeof(float), hipMemcpyDeviceToDevice, stream);
    hipMemcpyAsync(bqkv + 4096, bv, 512 * sizeof(float), hipMemcpyDeviceToDevice, stream);

    conv_bf_k<<<3584, 256, 0, stream>>>(hidden, hbf, (long)T_SEQ * HID);
    tconv_k<<<dim3(56, 56), 256, 0, stream>>>(wq, wqbt, HID, HID);
    tconv_k<<<dim3(8, 56), 256, 0, stream>>>(wk, wkbt, 512, HID);
    tconv_k<<<dim3(8, 56), 256, 0, stream>>>(wv, wvbt, 512, HID);

    // fused Q/K/V projection: Bt = [wq^T; wk^T; wv^T] (4608 rows), one launch
    gemm_bt_k<<<dim3(36, 16), 256, 0, stream>>>(hbf, HID, wqbt, HID, bqkv, qbuf, HID,
                                                HID, 3, kbuf);

    rope_k<<<(T_SEQ * NH * 64) / 256, 256, 0, stream>>>(qbuf, pos, HID, NH);
    rope_k<<<(T_SEQ * NKV * 64) / 256, 256, 0, stream>>>(kbuf, pos, 512, NKV);

    attn5_k<<<dim3(16, 28), 256, 0, stream>>>(qbuf, HID, kbuf, 512, vt, attnb, HID);

    // wo^T (reuses wq^T region, dead after QKV-GEMM)
    tconv_k<<<dim3(56, 56), 256, 0, stream>>>(wo, wobt, HID, HID);

    gemm_bt_k<<<dim3(28, 16), 256, 0, stream>>>(attnb, HID, wobt, HID, nullptr,
                                                outf, HID, HID, 1, nullptr);
  } else {
    // ---- fallback: fp32-reading path (ws >= 4,194,308) ----
    bf16_t* kbuf = (bf16_t*)ws;
    bf16_t* vt = (bf16_t*)(ws + 2097152);
    bf16_t* acopy = (bf16_t*)ws;
    int* flag = (int*)(ws + 4194304);

    hipMemsetAsync(flag, 64, 4, stream);  // 0x40404040 > 32 -> fp32 inputs

    gemm_nt_k<<<dim3(28, 16), 256, 0, stream>>>(hidden, HID, wq, HID, bq, qbuf, HID,
                                                HID, 1, 1, 0, 0, flag);
    gemm_nt_k<<<dim3(4, 16), 256, 0, stream>>>(hidden, HID, wk, 512, bk, kbuf, 512,
                                               HID, 1, 1, 0, 0, flag);
    gemm_nt_k<<<dim3(4, 16), 256, 0, stream>>>(hidden, HID, wv, 512, bv, vt, T_SEQ,
                                               HID, 1, 1, 1, 0, flag);

    rope_k<<<(T_SEQ * NH * 64) / 256, 256, 0, stream>>>(qbuf, pos, HID, NH);
    rope_k<<<(T_SEQ * NKV * 64) / 256, 256, 0, stream>>>(kbuf, pos, 512, NKV);

    attn5_k<<<dim3(16, 28), 256, 0, stream>>>(qbuf, HID, kbuf, 512, vt, attn_hi, HID);

    hipMemcpyAsync(acopy, attn_hi + (size_t)1536 * HID, (size_t)512 * HID * 2,
                   hipMemcpyDeviceToDevice, stream);
    gemm_nt_k<<<dim3(28, 8), 256, 0, stream>>>(attn_hi, HID, wo, HID, nullptr,
                                               outf, HID, HID, 0, 1, 0, 1, flag);
    gemm_nt_k<<<dim3(28, 4), 256, 0, stream>>>(attn_hi + (size_t)1024 * HID, HID, wo, HID,
                                               nullptr, outf + (size_t)1024 * HID, HID,
                                               HID, 0, 1, 0, 1, flag);
    gemm_nt_k<<<dim3(28, 4), 256, 0, stream>>>(acopy, HID, wo, HID,
                                               nullptr, outf + (size_t)1536 * HID, HID,
                                               HID, 0, 1, 0, 1, flag);
  }
}

// Round 9
// 492.103 us; speedup vs baseline: 1.1764x; 1.0573x over previous
//
#include <hip/hip_runtime.h>

typedef __bf16 bf16_t;
typedef __attribute__((ext_vector_type(8))) __bf16 bf16x8;
typedef __attribute__((ext_vector_type(4))) float floatx4;

#define T_SEQ 2048
#define HID 3584
#define NH 28
#define NKV 4
#define HD 128
#define GQA 7
#define SCALE_F 0.08838834764831845f
// SCALE_F * log2(e): QK^T directly in log2 domain (exp2 = 1 instr)
#define QSCALE_LOG2 0.1275179100693744f

// ---------------- fp32 -> bf16 conversion (n % 2048 == 0) ----------------
__global__ void conv_bf_k(const float* __restrict__ src, bf16_t* __restrict__ dst, long n) {
  const long i = ((long)blockIdx.x * 256 + threadIdx.x) * 8;
  if (i >= n) return;
  const floatx4 a = *(const floatx4*)(src + i);
  const floatx4 b = *(const floatx4*)(src + i + 4);
  bf16x8 r;
  r[0] = (bf16_t)a[0]; r[1] = (bf16_t)a[1]; r[2] = (bf16_t)a[2]; r[3] = (bf16_t)a[3];
  r[4] = (bf16_t)b[0]; r[5] = (bf16_t)b[1]; r[6] = (bf16_t)b[2]; r[7] = (bf16_t)b[3];
  *(bf16x8*)(dst + i) = r;
}

// ---------------- bias concat: dst[0:3584)=bq, [3584:4096)=bk, [4096:4608)=bv ----------------
__global__ void bias_cat_k(const float* __restrict__ bq, const float* __restrict__ bk,
                           const float* __restrict__ bv, float* __restrict__ dst) {
  const int i = blockIdx.x * 256 + threadIdx.x;
  if (i < 3584) dst[i] = bq[i];
  else if (i < 4096) dst[i] = bk[i - 3584];
  else if (i < 4608) dst[i] = bv[i - 4096];
}

// ---------------- transposing fp32 -> bf16: dst[N][K] = (bf16)src[K][N]^T ----------------
__global__ __launch_bounds__(256) void tconv_k(const float* __restrict__ src,
                                               bf16_t* __restrict__ dst, long N, long K) {
  __shared__ alignas(16) bf16_t t[64][72];
  const long k0 = (long)blockIdx.y * 64, n0 = (long)blockIdx.x * 64;
  const int tid = threadIdx.x;
  const int rr = tid >> 4;
  const int cc = (tid & 15) * 4;
#pragma unroll
  for (int i = 0; i < 4; ++i) {
    const int r = rr + i * 16;
    const floatx4 v = *(const floatx4*)(src + (k0 + r) * N + n0 + cc);
#pragma unroll
    for (int j = 0; j < 4; ++j) t[cc + j][r] = (bf16_t)v[j];
  }
  __syncthreads();
#pragma unroll
  for (int i = 0; i < 2; ++i) {
    const int J = i * 256 + tid;
    const int n = J >> 3, c8 = (J & 7) * 8;
    *(bf16x8*)(dst + (n0 + n) * K + k0 + c8) = *(const bf16x8*)(&t[n][c8]);
  }
}

// ---------------- fused wk+wv transpose: dst[1024][K] = [(bf16)wk^T ; (bf16)wv^T] ----------------
// grid (16, 56): blockIdx.x<8 -> wk cols, else wv. dst rows 0-511 = wk^T, 512-1023 = wv^T.
__global__ __launch_bounds__(256) void tconv_kv_k(const float* __restrict__ wk,
                                                  const float* __restrict__ wv,
                                                  bf16_t* __restrict__ dst, long K) {
  __shared__ alignas(16) bf16_t t[64][72];
  const int bx = blockIdx.x;
  const float* src = (bx < 8) ? wk : wv;
  const long n0s = (long)(bx & 7) * 64;   // col in source [K][512]
  const long n0d = (long)bx * 64;         // row in combined dst [1024][K]
  const long k0 = (long)blockIdx.y * 64;
  const int tid = threadIdx.x;
  const int rr = tid >> 4;
  const int cc = (tid & 15) * 4;
#pragma unroll
  for (int i = 0; i < 4; ++i) {
    const int r = rr + i * 16;
    const floatx4 v = *(const floatx4*)(src + (k0 + r) * 512 + n0s + cc);
#pragma unroll
    for (int j = 0; j < 4; ++j) t[cc + j][r] = (bf16_t)v[j];
  }
  __syncthreads();
#pragma unroll
  for (int i = 0; i < 2; ++i) {
    const int J = i * 256 + tid;
    const int n = J >> 3, c8 = (J & 7) * 8;
    *(bf16x8*)(dst + (n0d + n) * K + k0 + c8) = *(const bf16x8*)(&t[n][c8]);
  }
}

// load 8 contiguous elements as bf16x8, converting from fp32 if f32 is set
__device__ __forceinline__ bf16x8 ld8(const void* p, long idx, bool f32) {
  if (f32) {
    const float* q = (const float*)p + idx;
    const floatx4 u = *(const floatx4*)q;
    const floatx4 v = *(const floatx4*)(q + 4);
    bf16x8 r;
    r[0] = (bf16_t)u[0]; r[1] = (bf16_t)u[1]; r[2] = (bf16_t)u[2]; r[3] = (bf16_t)u[3];
    r[4] = (bf16_t)v[0]; r[5] = (bf16_t)v[1]; r[6] = (bf16_t)v[2]; r[7] = (bf16_t)v[3];
    return r;
  }
  return *(const bf16x8*)((const bf16_t*)p + idx);
}

__device__ __forceinline__ void gld16(const bf16_t* g, bf16_t* l) {
  __builtin_amdgcn_global_load_lds(
      (const __attribute__((address_space(1))) unsigned int*)(const void*)g,
      (__attribute__((address_space(3))) unsigned int*)(void*)l, 16, 0, 0);
}

// ---------------- GEMM (fast path): C[M][N] = A[M][K] @ Bt[N][K]^T (+fp32 bias) ----------------
// R6-proven best point: 128x128 tile, BK=32, 256 threads, LDS double-buffered (32KB),
// global_load_lds(16B) staging, counted vmcnt(4) + raw s_barrier (next tile's 4 loads
// stay in flight across the barrier). Chunk swizzle (rule #21, validated conflict-free):
// slot (row,c) holds global chunk c ^ ((row>>1)&3), applied on the per-lane GLOBAL
// source (dest lane-linear) and on fragment reads. BK=64 (R8) and 256² 8-phase (R7)
// both regressed: occupancy/grid-tail losses exceed barrier savings at this shape.
// mode 0: bf16 C. mode 1: fp32 C. mode 3: fused QKV epilogue (cc<3584 -> Cv bf16
// [row][ldc]; 3584<=cc<4096 -> Cv2[row][512]; cc>=4096 -> Cv2+1048576 transposed
// [cc-4096][T_SEQ]).
__global__ __launch_bounds__(256) void gemm_bt_k(
    const bf16_t* __restrict__ A, long lda,
    const bf16_t* __restrict__ Bt, long ldb,
    const float* __restrict__ bias, void* Cv, long ldc,
    int K, int mode, void* Cv2) {
  __shared__ alignas(16) bf16_t ldsA[2][128 * 32];
  __shared__ alignas(16) bf16_t ldsB[2][128 * 32];
  const int tid = threadIdx.x;
  const int lane = tid & 63;
  const int w = tid >> 6;
  const int wr = w >> 1, wc = w & 1;
  const int col = lane & 15, quad = lane >> 4;
  const long m0 = (long)blockIdx.y * 128, n0 = (long)blockIdx.x * 128;

  const int r0 = tid >> 2;              // row 0..63 (and +64)
  const int c0 = tid & 3;               // dest chunk
  const int cs = c0 ^ ((r0 >> 1) & 3);  // swizzled source chunk (same for row+64)
  const int r1 = 64 + r0;

  const bf16_t* Ab = A + m0 * lda + cs * 8;
  const bf16_t* Bb = Bt + n0 * ldb + cs * 8;

  floatx4 acc[4][4] = {};
  const int nt = K >> 5;

  auto stage = [&](int buf, int t) {
    const long k0 = (long)t << 5;
    gld16(Ab + (long)r0 * lda + k0, ldsA[buf] + tid * 8);
    gld16(Ab + (long)r1 * lda + k0, ldsA[buf] + (256 + tid) * 8);
    gld16(Bb + (long)r0 * ldb + k0, ldsB[buf] + tid * 8);
    gld16(Bb + (long)r1 * ldb + k0, ldsB[buf] + (256 + tid) * 8);
  };

  stage(0, 0);
  for (int t = 0; t < nt; ++t) {
    const int cur = t & 1;
    stage(cur ^ 1, (t + 1 == nt) ? 0 : t + 1);  // wrap keeps vmcnt uniform; harmless re-load
    __builtin_amdgcn_sched_barrier(0);
    asm volatile("s_waitcnt vmcnt(4)" ::: "memory");  // own cur-tile loads done; next 4 in flight
    __builtin_amdgcn_sched_barrier(0);
    __builtin_amdgcn_s_barrier();                     // all waves' cur-tile loads done
    __builtin_amdgcn_sched_barrier(0);
    bf16x8 af[4], bf[4];
#pragma unroll
    for (int i = 0; i < 4; ++i) {
      const int ra = wr * 64 + i * 16 + col;
      af[i] = *(const bf16x8*)(ldsA[cur] + ra * 32 + (quad ^ ((ra >> 1) & 3)) * 8);
    }
#pragma unroll
    for (int j = 0; j < 4; ++j) {
      const int rb = wc * 64 + j * 16 + col;
      bf[j] = *(const bf16x8*)(ldsB[cur] + rb * 32 + (quad ^ ((rb >> 1) & 3)) * 8);
    }
#pragma unroll
    for (int i = 0; i < 4; ++i)
#pragma unroll
      for (int j = 0; j < 4; ++j)
        acc[i][j] = __builtin_amdgcn_mfma_f32_16x16x32_bf16(af[i], bf[j], acc[i][j], 0, 0, 0);
    __builtin_amdgcn_sched_barrier(0);
    __builtin_amdgcn_s_barrier();  // all waves done reading cur before it is restaged
    __builtin_amdgcn_sched_barrier(0);
  }

#pragma unroll
  for (int i = 0; i < 4; ++i) {
#pragma unroll
    for (int j = 0; j < 4; ++j) {
      const long row0 = m0 + wr * 64 + i * 16 + quad * 4;
      const long cc = n0 + wc * 64 + j * 16 + col;
      const float bvv = bias ? bias[cc] : 0.f;
#pragma unroll
      for (int r = 0; r < 4; ++r) {
        const float v = acc[i][j][r] + bvv;
        if (mode == 0)      ((bf16_t*)Cv)[(row0 + r) * ldc + cc] = (bf16_t)v;
        else if (mode == 1) ((float*)Cv)[(row0 + r) * ldc + cc] = v;
        else {
          if (cc < 3584)      ((bf16_t*)Cv)[(row0 + r) * ldc + cc] = (bf16_t)v;
          else if (cc < 4096) ((bf16_t*)Cv2)[(row0 + r) * 512 + (cc - 3584)] = (bf16_t)v;
          else ((bf16_t*)Cv2)[1048576 + (cc - 4096) * (long)T_SEQ + (row0 + r)] = (bf16_t)v;
        }
      }
    }
  }
}

// ---------------- GEMM (fallback): C[M][N] = A[M][K] @ B[K][N] (+fp32 bias) ----------------
__global__ __launch_bounds__(256) void gemm_nt_k(
    const void* A, long lda, const void* B, long ldb,
    const float* bias, void* Cv, long ldc,
    int K, int aMode, int bMode, int transC, int c32, const int* flag) {
  __shared__ alignas(16) bf16_t ldsA[128 * 32];
  __shared__ alignas(16) unsigned int ldsB32[128 * 16];
  const int f = *flag;
  const bool aF32 = aMode && (f > 32);
  const bool bF32 = bMode && (f > 32);
  const int tid = threadIdx.x;
  const int lane = tid & 63;
  const int w = tid >> 6;
  const int wr = w >> 1, wc = w & 1;
  const int col = lane & 15, quad = lane >> 4;
  const long m0 = (long)blockIdx.y * 128, n0 = (long)blockIdx.x * 128;

  const int ar1 = tid >> 2, ak = (tid & 3) * 8;
  const int ar2 = 64 + ar1;
  const int kk = (tid >> 4) * 2;
  const int nn = (tid & 15) * 8;
  const int kp = kk >> 1;

  floatx4 acc[4][4] = {};

  for (int k0 = 0; k0 < K; k0 += 32) {
    const bf16x8 a1 = ld8(A, (m0 + ar1) * lda + k0 + ak, aF32);
    const bf16x8 a2 = ld8(A, (m0 + ar2) * lda + k0 + ak, aF32);
    const bf16x8 b0 = ld8(B, (long)(k0 + kk) * ldb + n0 + nn, bF32);
    const bf16x8 b1 = ld8(B, (long)(k0 + kk + 1) * ldb + n0 + nn, bF32);
    __syncthreads();
    *(bf16x8*)(ldsA + ar1 * 32 + ak) = a1;
    *(bf16x8*)(ldsA + ar2 * 32 + ak) = a2;
#pragma unroll
    for (int j = 0; j < 8; ++j) {
      const int n = nn + j;
      const int pk = ((((kp >> 2) ^ ((n >> 3) & 3)) << 2) | (kp & 3));
      union { struct { bf16_t lo, hi; } s; unsigned int u; } cv;
      cv.s.lo = b0[j];
      cv.s.hi = b1[j];
      ldsB32[n * 16 + pk] = cv.u;
    }
    __syncthreads();
    bf16x8 af[4], bfv[4];
#pragma unroll
    for (int i = 0; i < 4; ++i)
      af[i] = *(const bf16x8*)(ldsA + (wr * 64 + i * 16 + col) * 32 + quad * 8);
#pragma unroll
    for (int j = 0; j < 4; ++j) {
      const int n = wc * 64 + j * 16 + col;
      const int blk = quad ^ ((n >> 3) & 3);
      bfv[j] = *(const bf16x8*)((const bf16_t*)(ldsB32 + n * 16 + blk * 4));
    }
#pragma unroll
    for (int i = 0; i < 4; ++i)
#pragma unroll
      for (int jj = 0; jj < 4; ++jj)
        acc[i][jj] = __builtin_amdgcn_mfma_f32_16x16x32_bf16(af[i], bfv[jj], acc[i][jj], 0, 0, 0);
  }

#pragma unroll
  for (int i = 0; i < 4; ++i) {
#pragma unroll
    for (int j = 0; j < 4; ++j) {
      const long row0 = m0 + wr * 64 + i * 16 + quad * 4;
      const long cc = n0 + wc * 64 + j * 16 + col;
      const float bvv = bias ? bias[cc] : 0.f;
#pragma unroll
      for (int r = 0; r < 4; ++r) {
        const float v = acc[i][j][r] + bvv;
        if (transC)   ((bf16_t*)Cv)[cc * ldc + (row0 + r)] = (bf16_t)v;
        else if (c32) ((float*)Cv)[(row0 + r) * ldc + cc] = v;
        else          ((bf16_t*)Cv)[(row0 + r) * ldc + cc] = (bf16_t)v;
      }
    }
  }
}

// ---------------- fused RoPE: qb [T][HID] (NH heads) + kb [T][512] (NKV heads) ----------------
__global__ void rope2_k(bf16_t* __restrict__ qb, bf16_t* __restrict__ kb,
                        const int* __restrict__ pos) {
  const int idx = blockIdx.x * 256 + threadIdx.x;
  const int qtot = T_SEQ * NH * 64;
  bf16_t* buf;
  long ld;
  int nheads, id;
  if (idx < qtot) { buf = qb; ld = HID; nheads = NH; id = idx; }
  else { buf = kb; ld = 512; nheads = NKV; id = idx - qtot; }
  const int d = id & 63;
  const int th = id >> 6;
  const int h = th % nheads;
  const int t = th / nheads;
  const float inv = exp2f((float)d * (-19.931568569324174f / 64.f));
  const float ang = (float)pos[t] * inv;
  float sn, cs;
  __sincosf(ang, &sn, &cs);
  bf16_t* p = buf + (long)t * ld + h * HD + d;
  const float x1 = (float)p[0];
  const float x2 = (float)p[64];
  p[0] = (bf16_t)(x1 * cs - x2 * sn);
  p[64] = (bf16_t)(x2 * cs + x1 * sn);
}

// ---------------- RoPE (fallback path, single buffer) ----------------
__global__ void rope_k(bf16_t* buf, const int* __restrict__ pos, long ld, int nheads) {
  const int idx = blockIdx.x * 256 + threadIdx.x;
  const int total = T_SEQ * nheads * 64;
  if (idx >= total) return;
  const int d = idx & 63;
  const int th = idx >> 6;
  const int h = th % nheads;
  const int t = th / nheads;
  const float inv = exp2f((float)d * (-19.931568569324174f / 64.f));
  const float ang = (float)pos[t] * inv;
  float sn, cs;
  __sincosf(ang, &sn, &cs);
  bf16_t* p = buf + (long)t * ld + h * HD + d;
  const float x1 = (float)p[0];
  const float x2 = (float)p[64];
  p[0] = (bf16_t)(x1 * cs - x2 * sn);
  p[64] = (bf16_t)(x2 * cs + x1 * sn);
}

// ---------------- flash attention v5: 4 waves x 32 q-rows ----------------
// grid (16, 28), block 256 = 4 waves x 32 q-rows (2 subtiles of 16), s-tile = 64.
// Staging/pipeline: global_load_lds 16B, counted vmcnt(8), raw s_barrier, XOR-swizzled
// chunks; log2-domain softmax, per-16-row group max, ones-MFMA row-sum, defer-max THR=12.
__global__ __launch_bounds__(256, 2) void attn5_k(
    const bf16_t* __restrict__ q, long qs,
    const bf16_t* __restrict__ k, long ks,
    const bf16_t* __restrict__ vt,  // [512][2048] (hkv*128+d major, s minor)
    bf16_t* __restrict__ out, long os) {
  __shared__ alignas(16) bf16_t ldsK[2][64 * 128];  // 16KB x2
  __shared__ alignas(16) bf16_t ldsV[2][128 * 64];  // 16KB x2
  __shared__ alignas(16) bf16_t pbuf[4][32 * 64];   // per-wave P (32 rows), 4KB/wave

  const int h = blockIdx.y;
  const long hkvHD = (long)(h / GQA) * HD;
  const int tid = threadIdx.x;
  const int lane = tid & 63;
  const int w = tid >> 6;
  const int col = lane & 15, quad = lane >> 4;
  const int t0 = blockIdx.x * 128 + w * 32;

  auto stage = [&](int buf, int t) {
    const long s0 = (long)t * 64;
#pragma unroll
    for (int i = 0; i < 4; ++i) {
      const int J = i * 256 + tid;
      {  // K: 64 rows x 16 chunks
        const int row = J >> 4;
        const int cs = (J & 15) ^ (row & 7);
        gld16(k + (s0 + row) * ks + hkvHD + cs * 8, &ldsK[buf][J * 8]);
      }
      {  // V: 128 rows x 8 chunks
        const int row = J >> 3;
        const int cs = (J & 7) ^ (row & 7);
        gld16(vt + (hkvHD + row) * T_SEQ + s0 + cs * 8, &ldsV[buf][J * 8]);
      }
    }
  };

  bf16x8 aq[2][4];
#pragma unroll
  for (int sub = 0; sub < 2; ++sub) {
    const bf16_t* qp = q + (long)(t0 + sub * 16 + col) * qs + h * HD + quad * 8;
#pragma unroll
    for (int c = 0; c < 4; ++c) {
      aq[sub][c] = *(const bf16x8*)(qp + c * 32);
#pragma unroll
      for (int e = 0; e < 8; ++e)
        aq[sub][c][e] = (bf16_t)((float)aq[sub][c][e] * QSCALE_LOG2);
    }
  }

  bf16x8 ones;
#pragma unroll
  for (int e = 0; e < 8; ++e) ones[e] = (bf16_t)1.0f;

  floatx4 O[2][8] = {};
  float m_w[2] = {-1e30f, -1e30f};
  float l_i[2][4] = {};

  stage(0, 0);
  for (int t = 0; t < 32; ++t) {
    const int cur = t & 1;
    stage(cur ^ 1, (t + 1) & 31);
    __builtin_amdgcn_sched_barrier(0);
    asm volatile("s_waitcnt vmcnt(8)" ::: "memory");
    __builtin_amdgcn_sched_barrier(0);
    __builtin_amdgcn_s_barrier();
    __builtin_amdgcn_sched_barrier(0);

    // ---- S = q . K^T (log2 units); bk shared across both q-subtiles ----
    floatx4 S[2][4] = {};
    __builtin_amdgcn_s_setprio(1);
#pragma unroll
    for (int nt = 0; nt < 4; ++nt) {
      const int row = nt * 16 + col;
#pragma unroll
      for (int c = 0; c < 4; ++c) {
        const int cs = (c * 4 + quad) ^ (row & 7);
        const bf16x8 bk = *(const bf16x8*)(&ldsK[cur][row * 128 + cs * 8]);
        S[0][nt] = __builtin_amdgcn_mfma_f32_16x16x32_bf16(aq[0][c], bk, S[0][nt], 0, 0, 0);
        S[1][nt] = __builtin_amdgcn_mfma_f32_16x16x32_bf16(aq[1][c], bk, S[1][nt], 0, 0, 0);
      }
    }
    __builtin_amdgcn_s_setprio(0);

    // ---- per-subtile group max + defer-max rescale (wave-uniform branch) ----
#pragma unroll
    for (int sub = 0; sub < 2; ++sub) {
      float mx = S[sub][0][0];
#pragma unroll
      for (int nt = 0; nt < 4; ++nt)
#pragma unroll
        for (int r = 0; r < 4; ++r) mx = fmaxf(mx, S[sub][nt][r]);
#pragma unroll
      for (int off = 1; off < 64; off <<= 1)
        mx = fmaxf(mx, __shfl_xor(mx, off, 64));
      if (mx > m_w[sub] + 12.0f) {
        const float alpha = exp2f(m_w[sub] - mx);
        m_w[sub] = mx;
#pragma unroll
        for (int r = 0; r < 4; ++r) l_i[sub][r] *= alpha;
#pragma unroll
        for (int dt = 0; dt < 8; ++dt)
#pragma unroll
          for (int r = 0; r < 4; ++r) O[sub][dt][r] *= alpha;
      }
    }

    // ---- P = exp2(S - m), store to swizzled pbuf ----
#pragma unroll
    for (int sub = 0; sub < 2; ++sub)
#pragma unroll
      for (int r = 0; r < 4; ++r) {
        const int mrow = sub * 16 + quad * 4 + r;
#pragma unroll
        for (int nt = 0; nt < 4; ++nt) {
          const float p = exp2f(S[sub][nt][r] - m_w[sub]);
          const int cs = (nt * 2 + (col >> 3)) ^ (mrow & 7);
          pbuf[w][mrow * 64 + cs * 8 + (col & 7)] = (bf16_t)p;
        }
      }

    // ---- O += P @ V ; bv shared across subtiles; row-sum via mfma(pa, ones) ----
    floatx4 Ssum[2] = {};
    __builtin_amdgcn_s_setprio(1);
#pragma unroll
    for (int kb = 0; kb < 2; ++kb) {
      const int csp = (kb * 4 + quad) ^ (col & 7);
      const bf16x8 pa0 = *(const bf16x8*)(&pbuf[w][(col) * 64 + csp * 8]);
      const bf16x8 pa1 = *(const bf16x8*)(&pbuf[w][(16 + col) * 64 + csp * 8]);
      Ssum[0] = __builtin_amdgcn_mfma_f32_16x16x32_bf16(pa0, ones, Ssum[0], 0, 0, 0);
      Ssum[1] = __builtin_amdgcn_mfma_f32_16x16x32_bf16(pa1, ones, Ssum[1], 0, 0, 0);
#pragma unroll
      for (int dt = 0; dt < 8; ++dt) {
        const int vrow = dt * 16 + col;
        const bf16x8 bv = *(const bf16x8*)(&ldsV[cur][vrow * 64 + csp * 8]);
        O[0][dt] = __builtin_amdgcn_mfma_f32_16x16x32_bf16(pa0, bv, O[0][dt], 0, 0, 0);
        O[1][dt] = __builtin_amdgcn_mfma_f32_16x16x32_bf16(pa1, bv, O[1][dt], 0, 0, 0);
      }
    }
    __builtin_amdgcn_s_setprio(0);
#pragma unroll
    for (int sub = 0; sub < 2; ++sub)
#pragma unroll
      for (int r = 0; r < 4; ++r) l_i[sub][r] += Ssum[sub][r];

    __builtin_amdgcn_sched_barrier(0);
    __builtin_amdgcn_s_barrier();
    __builtin_amdgcn_sched_barrier(0);
  }

#pragma unroll
  for (int sub = 0; sub < 2; ++sub) {
#pragma unroll
    for (int r = 0; r < 4; ++r) l_i[sub][r] = 1.f / l_i[sub][r];
#pragma unroll
    for (int dt = 0; dt < 8; ++dt) {
#pragma unroll
      for (int r = 0; r < 4; ++r) {
        const long trow = t0 + sub * 16 + quad * 4 + r;
        out[trow * os + h * HD + dt * 16 + col] = (bf16_t)(O[sub][dt][r] * l_i[sub][r]);
      }
    }
  }
}

extern "C" void kernel_launch(void* const* d_in, const int* in_sizes, int n_in,
                              void* d_out_v, int out_size, void* d_ws, size_t ws_size,
                              hipStream_t stream) {
  const int* pos = (const int*)d_in[0];
  const float* hidden = (const float*)d_in[1];
  const float* wq = (const float*)d_in[2];
  const float* bq = (const float*)d_in[3];
  const float* wk = (const float*)d_in[4];
  const float* bk = (const float*)d_in[5];
  const float* wv = (const float*)d_in[6];
  const float* bv = (const float*)d_in[7];
  const float* wo = (const float*)d_in[8];

  bf16_t* qbuf = (bf16_t*)d_out_v;                          // lower half of d_out (bf16 q)
  bf16_t* attn_hi = (bf16_t*)d_out_v + (size_t)T_SEQ * HID; // upper half (scratch / fallback)
  float* outf = (float*)d_out_v;

  char* ws = (char*)d_ws;
  const size_t NEED = 51904516;

  if (ws_size >= NEED) {
    // ---- fast path: bf16 operands, weights pre-transposed; QKV fused GEMM ----
    bf16_t* hbf  = (bf16_t*)ws;                  // [2048][3584]  (later: attn out)
    bf16_t* wqbt = (bf16_t*)(ws + 14680064);     // [3584][3584] = wq^T (later: wo^T)
    bf16_t* wkbt = (bf16_t*)(ws + 40370176);     // [512][3584]  = wk^T (contig after wqbt)
    bf16_t* kbuf = (bf16_t*)(ws + 47710208);     // [2048][512]
    bf16_t* vt   = (bf16_t*)(ws + 49807360);     // [512][2048]  (= kbuf + 1048576 elems)
    bf16_t* wobt = wqbt;
    bf16_t* attnb = hbf;
    float* bqkv = (float*)attn_hi;               // 4608 fp32 concat bias in d_out upper half

    bias_cat_k<<<18, 256, 0, stream>>>(bq, bk, bv, bqkv);
    conv_bf_k<<<3584, 256, 0, stream>>>(hidden, hbf, (long)T_SEQ * HID);
    tconv_k<<<dim3(56, 56), 256, 0, stream>>>(wq, wqbt, HID, HID);
    tconv_kv_k<<<dim3(16, 56), 256, 0, stream>>>(wk, wv, wkbt, HID);  // [wk^T; wv^T]

    // fused Q/K/V projection: Bt = [wq^T; wk^T; wv^T] (4608 rows), one launch
    gemm_bt_k<<<dim3(36, 16), 256, 0, stream>>>(hbf, HID, wqbt, HID, bqkv, qbuf, HID,
                                                HID, 3, kbuf);

    rope2_k<<<(T_SEQ * (NH + NKV) * 64) / 256, 256, 0, stream>>>(qbuf, kbuf, pos);

    attn5_k<<<dim3(16, 28), 256, 0, stream>>>(qbuf, HID, kbuf, 512, vt, attnb, HID);

    // wo^T (reuses wq^T region, dead after QKV-GEMM)
    tconv_k<<<dim3(56, 56), 256, 0, stream>>>(wo, wobt, HID, HID);

    gemm_bt_k<<<dim3(28, 16), 256, 0, stream>>>(attnb, HID, wobt, HID, nullptr,
                                                outf, HID, HID, 1, nullptr);
  } else {
    // ---- fallback: fp32-reading path (ws >= 4,194,308) ----
    bf16_t* kbuf = (bf16_t*)ws;
    bf16_t* vt = (bf16_t*)(ws + 2097152);
    bf16_t* acopy = (bf16_t*)ws;
    int* flag = (int*)(ws + 4194304);

    hipMemsetAsync(flag, 64, 4, stream);  // 0x40404040 > 32 -> fp32 inputs

    gemm_nt_k<<<dim3(28, 16), 256, 0, stream>>>(hidden, HID, wq, HID, bq, qbuf, HID,
                                                HID, 1, 1, 0, 0, flag);
    gemm_nt_k<<<dim3(4, 16), 256, 0, stream>>>(hidden, HID, wk, 512, bk, kbuf, 512,
                                               HID, 1, 1, 0, 0, flag);
    gemm_nt_k<<<dim3(4, 16), 256, 0, stream>>>(hidden, HID, wv, 512, bv, vt, T_SEQ,
                                               HID, 1, 1, 1, 0, flag);

    rope_k<<<(T_SEQ * NH * 64) / 256, 256, 0, stream>>>(qbuf, pos, HID, NH);
    rope_k<<<(T_SEQ * NKV * 64) / 256, 256, 0, stream>>>(kbuf, pos, 512, NKV);

    attn5_k<<<dim3(16, 28), 256, 0, stream>>>(qbuf, HID, kbuf, 512, vt, attn_hi, HID);

    hipMemcpyAsync(acopy, attn_hi + (size_t)1536 * HID, (size_t)512 * HID * 2,
                   hipMemcpyDeviceToDevice, stream);
    gemm_nt_k<<<dim3(28, 8), 256, 0, stream>>>(attn_hi, HID, wo, HID, nullptr,
                                               outf, HID, HID, 0, 1, 0, 1, flag);
    gemm_nt_k<<<dim3(28, 4), 256, 0, stream>>>(attn_hi + (size_t)1024 * HID, HID, wo, HID,
                                               nullptr, outf + (size_t)1024 * HID, HID,
                                               HID, 0, 1, 0, 1, flag);
    gemm_nt_k<<<dim3(28, 4), 256, 0, stream>>>(acopy, HID, wo, HID,
                                               nullptr, outf + (size_t)1536 * HID, HID,
                                               HID, 0, 1, 0, 1, flag);
  }
}